// Round 11
// baseline (314.611 us; speedup 1.0000x reference)
//
#include <hip/hip_runtime.h>
#include <math.h>

// ---------------- workspace layout (bytes) ----------------
// [0)            double sum
// [16)           unsigned minkey[64]
// [16+256)       unsigned maxkey[64]
// [16+512)       float u7[7]   (separable 1-D gaussian weights)

__device__ __forceinline__ unsigned fkey(float f) {
    unsigned u = __float_as_uint(f);
    return (u & 0x80000000u) ? ~u : (u | 0x80000000u);
}
__device__ __forceinline__ float funkey(unsigned k) {
    return __uint_as_float((k & 0x80000000u) ? (k & 0x7FFFFFFFu) : ~k);
}

__global__ void init_ws(const float* __restrict__ w, float* __restrict__ u7,
                        unsigned* __restrict__ mink, unsigned* __restrict__ maxk,
                        double* __restrict__ sum) {
    int t = threadIdx.x;
    if (t == 0) *sum = 0.0;
    if (t < 64) { mink[t] = 0xFFFFFFFFu; maxk[t] = 0u; }
    if (t < 7) {
        float s = 0.f;
        for (int j = 0; j < 7; ++j) s += w[t * 7 + j];
        u7[t] = s;  // row sums of normalized 2-D window == 1-D weights
    }
}

// per-batch min/max of Y. 16 blocks per batch, 256 threads, float4 loads.
__global__ __launch_bounds__(256) void minmax_kernel(const float4* __restrict__ Y,
                                                     unsigned* __restrict__ mink,
                                                     unsigned* __restrict__ maxk) {
    int b = blockIdx.x >> 4, ch = blockIdx.x & 15;
    const float4* p = Y + (size_t)b * 65536 + (size_t)ch * 4096 + threadIdx.x;
    float lmin = INFINITY, lmax = -INFINITY;
#pragma unroll
    for (int i = 0; i < 16; ++i) {
        float4 v = p[(size_t)i * 256];
        lmin = fminf(lmin, fminf(fminf(v.x, v.y), fminf(v.z, v.w)));
        lmax = fmaxf(lmax, fmaxf(fmaxf(v.x, v.y), fmaxf(v.z, v.w)));
    }
#pragma unroll
    for (int off = 32; off; off >>= 1) {
        lmin = fminf(lmin, __shfl_down(lmin, off));
        lmax = fmaxf(lmax, __shfl_down(lmax, off));
    }
    if ((threadIdx.x & 63) == 0) {
        atomicMin(&mink[b], fkey(lmin));
        atomicMax(&maxk[b], fkey(lmax));
    }
}

// ---------------------------------------------------------------------------
// Main SSIM kernel. r4 VERBATIM (5-channel, mod-7 macro-literal ring, 2x14
// step loop, 2-deep prefetch regs, proven 60 VGPR / no scratch) except ONE
// clean delta: LDS row buffers are per-wave (s[4][2][72]: each wave owns a
// 64-col strip + 3+3 halo entries) and the per-step __syncthreads() is
// REMOVED. All LDS communication is intra-wave; the DS pipe is in-order per
// wave, so ds_write -> ds_read RAW needs no barrier. Buffer alternation is
// ordered by may-alias analysis (same array). The compiler inserts counted
// per-wave vmcnt/lgkmcnt waits (no asm clobbers, no pointer variables --
// the two r10 failure suspects are removed). Waves free-run and de-phase, so
// VALU / LDS / VMEM overlap across the 4 waves instead of phase-locking at 38
// block-wide barriers (r4's ~35% stall).
// Tile: wave = 64 cols x 32 rows; block = 256 cols. Grid = 64*2*16 = 2048.
// ---------------------------------------------------------------------------
__global__ __launch_bounds__(256, 4) void ssim_kernel(const float* __restrict__ X,
                                                      const float* __restrict__ Yg,
                                                      const float* __restrict__ u7,
                                                      const unsigned* __restrict__ mink,
                                                      const unsigned* __restrict__ maxk,
                                                      double* __restrict__ sum) {
    __shared__ float2 s[4][2][72];     // [wave][buf][entry], entry = col-c0+3
    __shared__ float warpsum[4];

    const int blk  = blockIdx.x;
    const int b    = blk >> 5;         // image
    const int sub  = blk & 31;
    const int cs   = sub & 1;          // col strip (0..1)
    const int rs   = sub >> 1;         // row strip (0..15)
    const int t    = threadIdx.x;
    const int wv   = t >> 6;           // wave id (0..3)
    const int lane = t & 63;
    const int c0   = (cs << 8) + (wv << 6);   // wave's first output col
    const int r0   = rs << 5;

    float u[7];
#pragma unroll
    for (int i = 0; i < 7; ++i) u[i] = u7[i];

    const float dr = funkey(maxk[b]) - funkey(mink[b]);
    float C1 = 0.01f * dr; C1 *= C1;
    float C2 = 0.03f * dr; C2 *= C2;
    const float cn = 49.f / 48.f;

    const float* __restrict__ Xb = X  + ((size_t)b << 18);
    const float* __restrict__ Yb = Yg + ((size_t)b << 18);

    const int  c    = c0 + lane;                  // main col, always in-image
    const bool hasE = (lane < 6);                 // halo entries 0..2, 67..69
    const int  eL   = (lane < 3) ? lane : (lane + 64);
    const int  ecol = c0 + eL - 3;
    const bool eok  = (ecol >= 0) && (ecol < 512);
    const int  ec   = min(max(ecol, 0), 511);

    float fx[2], fy[2], ex[2], ey[2];             // prefetch regs (row parity)
    float phx[7], phy[7], phxx[7], phyy[7], phxy[7];  // mod-7 ring
    float ssacc = 0.f;

#define LOADROW(P, JJ) do {                                                   \
    int r_ = r0 - 3 + (JJ);                                                   \
    if (r_ >= 0 && r_ < 512) {   /* block-uniform branch */                   \
        const float* xp_ = Xb + ((size_t)r_ << 9);                            \
        const float* yp_ = Yb + ((size_t)r_ << 9);                            \
        fx[(P)] = xp_[c]; fy[(P)] = yp_[c];                                   \
        if (hasE) { ex[(P)] = eok ? xp_[ec] : 0.f;                            \
                    ey[(P)] = eok ? yp_[ec] : 0.f; }                          \
    } else {                                                                  \
        fx[(P)] = 0.f; fy[(P)] = 0.f; ex[(P)] = 0.f; ey[(P)] = 0.f;           \
    }                                                                         \
} while (0)

#define WRITEROW(P) do {                                                      \
    s[wv][(P)][lane + 3] = make_float2(fx[(P)], fy[(P)]);                     \
    if (hasE) s[wv][(P)][eL] = make_float2(ex[(P)], ey[(P)]);                 \
} while (0)

#define HBLUR(BUF, SLOT) do {                                                 \
    float hx_ = 0.f, hy_ = 0.f, hxx_ = 0.f, hyy_ = 0.f, hxy_ = 0.f;           \
    _Pragma("unroll")                                                         \
    for (int k_ = 0; k_ < 7; ++k_) {                                          \
        float2 v_ = s[wv][(BUF)][lane + k_];                                  \
        float wx_ = u[k_] * v_.x, wy_ = u[k_] * v_.y;                         \
        hx_ += wx_; hy_ += wy_;                                               \
        hxx_ = fmaf(wx_, v_.x, hxx_);                                         \
        hxy_ = fmaf(wx_, v_.y, hxy_);                                         \
        hyy_ = fmaf(wy_, v_.y, hyy_);                                         \
    }                                                                         \
    phx[(SLOT)] = hx_; phy[(SLOT)] = hy_;                                     \
    phxx[(SLOT)] = hxx_; phyy[(SLOT)] = hyy_; phxy[(SLOT)] = hxy_;            \
} while (0)

// vertical blur: tap k reads slot (J+1+k)%7 with weight u[k]
#define VS(a, J) fmaf(u[6], a[(J) % 7], fmaf(u[5], a[((J)+6) % 7],            \
               fmaf(u[4], a[((J)+5) % 7], fmaf(u[3], a[((J)+4) % 7],          \
               fmaf(u[2], a[((J)+3) % 7], fmaf(u[1], a[((J)+2) % 7],          \
               u[0] * a[((J)+1) % 7]))))))

#define EMIT(J) do {                                                          \
    float mux = VS(phx, (J)), muy = VS(phy, (J));                             \
    float mxx = VS(phxx, (J)), myy = VS(phyy, (J)), mxy = VS(phxy, (J));      \
    float mux2 = mux * mux, muy2 = muy * muy, muxy = mux * muy;               \
    float sxx = (mxx - mux2) * cn;                                            \
    float syy = (myy - muy2) * cn;                                            \
    float sxy = (mxy - muxy) * cn;                                            \
    float num = (2.f * muxy + C1) * (2.f * sxy + C2);                         \
    float den = (mux2 + muy2 + C1) * (sxx + syy + C2);                        \
    ssacc = fmaf(num, __builtin_amdgcn_rcpf(den), ssacc);                     \
} while (0)

#define PSTEP(J) do {                                                         \
    HBLUR((J) & 1, (J) % 7);                                                  \
    WRITEROW(((J) + 1) & 1);                                                  \
    LOADROW(((J) + 1) & 1, (J) + 3);                                          \
} while (0)

#define MSTEP(J) do {                                                         \
    HBLUR((J) & 1, (J) % 7);                                                  \
    EMIT(J);                                                                  \
    WRITEROW(((J) + 1) & 1);                                                  \
    LOADROW(((J) + 1) & 1, jb + (J) + 3);                                     \
} while (0)

#define MSTEP_NL(J) do {                                                      \
    HBLUR((J) & 1, (J) % 7);                                                  \
    EMIT(J);                                                                  \
    WRITEROW(((J) + 1) & 1);                                                  \
} while (0)

#define MSTEP_END(J) do {                                                     \
    HBLUR((J) & 1, (J) % 7);                                                  \
    EMIT(J);                                                                  \
} while (0)

    // pre-prologue: rows 0,1 loaded; row 0 staged to buf0; row 2 in flight
    LOADROW(0, 0);
    LOADROW(1, 1);
    WRITEROW(0);
    LOADROW(0, 2);

    // prologue: rows 0..5 fill ring slots 0..5 (loads rows 3..8)
    PSTEP(0); PSTEP(1); PSTEP(2); PSTEP(3); PSTEP(4); PSTEP(5);

    // main: rows 6..33 (outputs 0..27); loads rows 9..36
    for (int g = 0; g < 2; ++g) {
        const int jb = 14 * g;
        MSTEP(6);  MSTEP(7);  MSTEP(8);  MSTEP(9);  MSTEP(10); MSTEP(11); MSTEP(12);
        MSTEP(13); MSTEP(14); MSTEP(15); MSTEP(16); MSTEP(17); MSTEP(18); MSTEP(19);
    }

    // tail: rows 34..37 (outputs 28..31)
    {
        const int jb = 28;
        MSTEP(6);        // row 34, loads row 37
        MSTEP_NL(7);     // row 35
        MSTEP_NL(8);     // row 36, stages row 37
        MSTEP_END(9);    // row 37
    }

#undef LOADROW
#undef WRITEROW
#undef HBLUR
#undef VS
#undef EMIT
#undef PSTEP
#undef MSTEP
#undef MSTEP_NL
#undef MSTEP_END

    // block reduction: wave shuffle -> LDS -> one double atomic per block
#pragma unroll
    for (int off = 32; off; off >>= 1) ssacc += __shfl_down(ssacc, off);
    if (lane == 0) warpsum[wv] = ssacc;
    __syncthreads();
    if (t == 0) {
        double sm = (double)warpsum[0] + (double)warpsum[1] +
                    (double)warpsum[2] + (double)warpsum[3];
        atomicAdd(sum, sm);
    }
}

__global__ void finalize_kernel(const double* __restrict__ sum, float* __restrict__ out) {
    out[0] = (float)(1.0 - (*sum) / (64.0 * 512.0 * 512.0));
}

extern "C" void kernel_launch(void* const* d_in, const int* in_sizes, int n_in,
                              void* d_out, int out_size, void* d_ws, size_t ws_size,
                              hipStream_t stream) {
    const float* X = (const float*)d_in[0];
    const float* Y = (const float*)d_in[1];
    const float* W = (const float*)d_in[2];

    char* ws = (char*)d_ws;
    double* sum = (double*)(ws + 0);
    unsigned* mink = (unsigned*)(ws + 16);
    unsigned* maxk = (unsigned*)(ws + 16 + 256);
    float* u7 = (float*)(ws + 16 + 512);

    init_ws<<<1, 64, 0, stream>>>(W, u7, mink, maxk, sum);
    minmax_kernel<<<1024, 256, 0, stream>>>((const float4*)Y, mink, maxk);
    ssim_kernel<<<2048, 256, 0, stream>>>(X, Y, u7, mink, maxk, sum);
    finalize_kernel<<<1, 1, 0, stream>>>(sum, (float*)d_out);
}

// Round 12
// 239.280 us; speedup vs baseline: 1.3148x; 1.3148x over previous
//
#include <hip/hip_runtime.h>
#include <math.h>

// ---------------- workspace layout (bytes) ----------------
// [0)      double sum
// [16)     unsigned minkey[64]
// [272)    unsigned maxkey[64]
// [528)    float u7[7]
// [1024)   float zeros[64]   (OOB load source, zeroed every launch)

__device__ __forceinline__ unsigned fkey(float f) {
    unsigned u = __float_as_uint(f);
    return (u & 0x80000000u) ? ~u : (u | 0x80000000u);
}
__device__ __forceinline__ float funkey(unsigned k) {
    return __uint_as_float((k & 0x80000000u) ? (k & 0x7FFFFFFFu) : ~k);
}

// direct global->LDS 4B copy: dest = wave-uniform LDS base + lane*4,
// src = per-lane global address. No VGPR destination => no staging pressure.
__device__ __forceinline__ void gl2lds4(const float* g, float* l) {
    __builtin_amdgcn_global_load_lds(
        (const __attribute__((address_space(1))) void*)g,
        (__attribute__((address_space(3))) void*)l, 4, 0, 0);
}

__global__ void init_ws(const float* __restrict__ w, float* __restrict__ u7,
                        unsigned* __restrict__ mink, unsigned* __restrict__ maxk,
                        double* __restrict__ sum, float* __restrict__ zeros) {
    int t = threadIdx.x;
    if (t == 0) *sum = 0.0;
    if (t < 64) { mink[t] = 0xFFFFFFFFu; maxk[t] = 0u; zeros[t] = 0.f; }
    if (t < 7) {
        float s = 0.f;
        for (int j = 0; j < 7; ++j) s += w[t * 7 + j];
        u7[t] = s;  // row sums of normalized 2-D window == 1-D weights
    }
}

// per-batch min/max of Y. 16 blocks per batch, 256 threads, float4 loads.
__global__ __launch_bounds__(256) void minmax_kernel(const float4* __restrict__ Y,
                                                     unsigned* __restrict__ mink,
                                                     unsigned* __restrict__ maxk) {
    int b = blockIdx.x >> 4, ch = blockIdx.x & 15;
    const float4* p = Y + (size_t)b * 65536 + (size_t)ch * 4096 + threadIdx.x;
    float lmin = INFINITY, lmax = -INFINITY;
#pragma unroll
    for (int i = 0; i < 16; ++i) {
        float4 v = p[(size_t)i * 256];
        lmin = fminf(lmin, fminf(fminf(v.x, v.y), fminf(v.z, v.w)));
        lmax = fmaxf(lmax, fmaxf(fmaxf(v.x, v.y), fmaxf(v.z, v.w)));
    }
#pragma unroll
    for (int off = 32; off; off >>= 1) {
        lmin = fminf(lmin, __shfl_down(lmin, off));
        lmax = fmaxf(lmax, __shfl_down(lmax, off));
    }
    if ((threadIdx.x & 63) == 0) {
        atomicMin(&mink[b], fkey(lmin));
        atomicMax(&maxk[b], fkey(lmax));
    }
}

// ---------------------------------------------------------------------------
// Main SSIM kernel. r4 math verbatim (5-channel hblur, mod-7 register ring,
// 2x14-step literal schedule). Structural change: BARRIER-FREE per-wave tiles.
//  * wave = 64 output cols x 32 rows; per-wave LDS row ring xb/yb[7][72]
//    (entry e = col-c0-3+... e=lane covers cols c0-3..c0+60; e=64..69 halo
//    cols c0+61..c0+66 staged by lanes 0..5).
//  * staging via global_load_lds (no VGPR dest -> scheduler cannot create
//    register pressure by hoisting loads: the r10/r11 spill mechanism is
//    structurally impossible).
//  * exactly 4 gl2lds per wave per step; `s_waitcnt vmcnt(4)` at step start
//    guarantees row J landed (rows J+1,J+2 stay in flight; never vmcnt(0)
//    in-loop). FIFO: row J is strictly older than the newest 4 loads.
//  * OOB rows/cols: per-lane src redirected to zeroed ws region (count
//    stays uniform). No __syncthreads, no ds_write in the loop.
// Grid = 64 img * 2 colstrips * 16 rowstrips = 2048 blocks, 4 waves each.
// ---------------------------------------------------------------------------
__global__ __launch_bounds__(256, 4) void ssim_kernel(const float* __restrict__ X,
                                                      const float* __restrict__ Yg,
                                                      const float* __restrict__ u7,
                                                      const unsigned* __restrict__ mink,
                                                      const unsigned* __restrict__ maxk,
                                                      const float* __restrict__ zeros,
                                                      double* __restrict__ sum) {
    __shared__ float xb[4][7][72];     // [wave][buf = row%7][entry]
    __shared__ float yb[4][7][72];
    __shared__ float warpsum[4];

    const int blk  = blockIdx.x;
    const int b    = blk >> 5;         // image
    const int sub  = blk & 31;
    const int cs   = sub & 1;          // col strip (0..1)
    const int rs   = sub >> 1;         // row strip (0..15)
    const int t    = threadIdx.x;
    const int wv   = t >> 6;           // wave id (0..3)
    const int lane = t & 63;
    const int c0   = (cs << 8) + (wv << 6);   // wave's first output col
    const int r0   = rs << 5;

    float u[7];
#pragma unroll
    for (int i = 0; i < 7; ++i) u[i] = u7[i];

    const float dr = funkey(maxk[b]) - funkey(mink[b]);
    float C1 = 0.01f * dr; C1 *= C1;
    float C2 = 0.03f * dr; C2 *= C2;
    const float cn = 49.f / 48.f;

    const float* __restrict__ Xb = X  + ((size_t)b << 18);
    const float* __restrict__ Yb = Yg + ((size_t)b << 18);
    const float* zpl = zeros + lane;              // per-lane zero source

    const int  cm  = c0 - 3 + lane;               // main col (e = lane)
    const bool okm = (cm >= 0);                   // cm <= 508 always
    const int  chh = c0 + 61 + lane;              // halo col (e = 64+lane)
    const bool okh = (chh < 512);                 // chh >= 61 always

    float phx[7], phy[7], phxx[7], phyy[7], phxy[7];  // mod-7 ring
    float ssacc = 0.f;

#define WAITROW  asm volatile("s_waitcnt vmcnt(4)" ::: "memory")
#define WAITZERO asm volatile("s_waitcnt vmcnt(0)" ::: "memory")

// issue row JJ into buf B (B = JJ%7, frontend literal). 4 loads per wave.
#define ISSUE(B, JJ) do {                                                     \
    int r_ = r0 - 3 + (JJ);                                                   \
    bool rok_ = (r_ >= 0) && (r_ < 512);                                      \
    int rr_ = rok_ ? r_ : 0;                                                  \
    const float* xr_ = Xb + ((size_t)rr_ << 9);                               \
    const float* yr_ = Yb + ((size_t)rr_ << 9);                               \
    gl2lds4((rok_ && okm) ? (xr_ + cm) : zpl, &xb[wv][(B)][0]);               \
    gl2lds4((rok_ && okm) ? (yr_ + cm) : zpl, &yb[wv][(B)][0]);               \
    if (lane < 6) {                                                           \
        gl2lds4((rok_ && okh) ? (xr_ + chh) : zpl, &xb[wv][(B)][64]);         \
        gl2lds4((rok_ && okh) ? (yr_ + chh) : zpl, &yb[wv][(B)][64]);         \
    }                                                                         \
} while (0)

#define HBLUR(B, SLOT) do {                                                   \
    float hx_ = 0.f, hy_ = 0.f, hxx_ = 0.f, hyy_ = 0.f, hxy_ = 0.f;           \
    _Pragma("unroll")                                                         \
    for (int k_ = 0; k_ < 7; ++k_) {                                          \
        float xv_ = xb[wv][(B)][lane + k_];                                   \
        float yv_ = yb[wv][(B)][lane + k_];                                   \
        float wx_ = u[k_] * xv_, wy_ = u[k_] * yv_;                           \
        hx_ += wx_; hy_ += wy_;                                               \
        hxx_ = fmaf(wx_, xv_, hxx_);                                          \
        hxy_ = fmaf(wx_, yv_, hxy_);                                          \
        hyy_ = fmaf(wy_, yv_, hyy_);                                          \
    }                                                                         \
    phx[(SLOT)] = hx_; phy[(SLOT)] = hy_;                                     \
    phxx[(SLOT)] = hxx_; phyy[(SLOT)] = hyy_; phxy[(SLOT)] = hxy_;            \
} while (0)

// vertical blur: tap k reads slot (J+1+k)%7 with weight u[k]
#define VS(a, J) fmaf(u[6], a[(J) % 7], fmaf(u[5], a[((J)+6) % 7],            \
               fmaf(u[4], a[((J)+5) % 7], fmaf(u[3], a[((J)+4) % 7],          \
               fmaf(u[2], a[((J)+3) % 7], fmaf(u[1], a[((J)+2) % 7],          \
               u[0] * a[((J)+1) % 7]))))))

#define EMIT(J) do {                                                          \
    float mux = VS(phx, (J)), muy = VS(phy, (J));                             \
    float mxx = VS(phxx, (J)), myy = VS(phyy, (J)), mxy = VS(phxy, (J));      \
    float mux2 = mux * mux, muy2 = muy * muy, muxy = mux * muy;               \
    float sxx = (mxx - mux2) * cn;                                            \
    float syy = (myy - muy2) * cn;                                            \
    float sxy = (mxy - muxy) * cn;                                            \
    float num = (2.f * muxy + C1) * (2.f * sxy + C2);                         \
    float den = (mux2 + muy2 + C1) * (sxx + syy + C2);                        \
    ssacc = fmaf(num, __builtin_amdgcn_rcpf(den), ssacc);                     \
} while (0)

#define PSTEP(J) do {                                                         \
    WAITROW;                                                                  \
    HBLUR((J) % 7, (J) % 7);                                                  \
    ISSUE(((J) + 2) % 7, (J) + 2);                                            \
} while (0)

#define MSTEP(J) do {                                                         \
    WAITROW;                                                                  \
    HBLUR((J) % 7, (J) % 7);                                                  \
    EMIT(J);                                                                  \
    ISSUE(((J) + 2) % 7, jb + (J) + 2);                                       \
} while (0)

#define MSTEP_NL(J) do {                                                      \
    WAITROW;                                                                  \
    HBLUR((J) % 7, (J) % 7);                                                  \
    EMIT(J);                                                                  \
} while (0)

#define MSTEP_END(J) do {                                                     \
    WAITZERO;                                                                 \
    HBLUR((J) % 7, (J) % 7);                                                  \
    EMIT(J);                                                                  \
} while (0)

    // pre-prologue: rows 0,1 in flight (8 outstanding loads)
    ISSUE(0, 0);
    ISSUE(1, 1);

    // prologue: rows 0..5 fill ring slots 0..5 (issue rows 2..7)
    PSTEP(0); PSTEP(1); PSTEP(2); PSTEP(3); PSTEP(4); PSTEP(5);

    // main: rows 6..33 (outputs 0..27); issues rows 8..35
    for (int g = 0; g < 2; ++g) {
        const int jb = 14 * g;   // jb % 7 == 0 and % 2 == 0: literals hold
        MSTEP(6);  MSTEP(7);  MSTEP(8);  MSTEP(9);  MSTEP(10); MSTEP(11); MSTEP(12);
        MSTEP(13); MSTEP(14); MSTEP(15); MSTEP(16); MSTEP(17); MSTEP(18); MSTEP(19);
    }

    // tail: rows 34..37 (outputs 28..31); issues rows 36,37
    {
        const int jb = 28;
        MSTEP(6);        // row 34, issues row 36 (buf (6+2)%7=1 == 36%7)
        MSTEP(7);        // row 35, issues row 37 (buf 2 == 37%7)
        MSTEP_NL(8);     // row 36
        MSTEP_END(9);    // row 37
    }

#undef WAITROW
#undef WAITZERO
#undef ISSUE
#undef HBLUR
#undef VS
#undef EMIT
#undef PSTEP
#undef MSTEP
#undef MSTEP_NL
#undef MSTEP_END

    // block reduction: wave shuffle -> LDS -> one double atomic per block
#pragma unroll
    for (int off = 32; off; off >>= 1) ssacc += __shfl_down(ssacc, off);
    if (lane == 0) warpsum[wv] = ssacc;
    __syncthreads();
    if (t == 0) {
        double sm = (double)warpsum[0] + (double)warpsum[1] +
                    (double)warpsum[2] + (double)warpsum[3];
        atomicAdd(sum, sm);
    }
}

__global__ void finalize_kernel(const double* __restrict__ sum, float* __restrict__ out) {
    out[0] = (float)(1.0 - (*sum) / (64.0 * 512.0 * 512.0));
}

extern "C" void kernel_launch(void* const* d_in, const int* in_sizes, int n_in,
                              void* d_out, int out_size, void* d_ws, size_t ws_size,
                              hipStream_t stream) {
    const float* X = (const float*)d_in[0];
    const float* Y = (const float*)d_in[1];
    const float* W = (const float*)d_in[2];

    char* ws = (char*)d_ws;
    double* sum = (double*)(ws + 0);
    unsigned* mink = (unsigned*)(ws + 16);
    unsigned* maxk = (unsigned*)(ws + 272);
    float* u7 = (float*)(ws + 528);
    float* zeros = (float*)(ws + 1024);

    init_ws<<<1, 64, 0, stream>>>(W, u7, mink, maxk, sum, zeros);
    minmax_kernel<<<1024, 256, 0, stream>>>((const float4*)Y, mink, maxk);
    ssim_kernel<<<2048, 256, 0, stream>>>(X, Y, u7, mink, maxk, zeros, sum);
    finalize_kernel<<<1, 1, 0, stream>>>(sum, (float*)d_out);
}